// Round 5
// baseline (368.495 us; speedup 1.0000x reference)
//
#include <hip/hip_runtime.h>

// RelationNet: B=16, N=16, K=8, H=128, 2H=256
// out[b,n1,o] = mean over (n2,k1,k2) of relu(W3 relu(W2 relu(A[b,n1,k1]+Bv[b,n2,k2])))
// A = enc @ W1[:, :128]^T, Bv = enc @ W1[:, 128:]^T  (layer 1 factors).
// Layers 2/3 on matrix cores. R4 numerics: W-only 2-term split
//   y = xh*(Wh + Wl), xh = fp16(x) RN  -> 2 MFMAs per product.
// x-rounding (2^-11 rel, unbiased) dominates error; predicted absmax ~5e-4.

typedef _Float16 f16;
typedef __attribute__((ext_vector_type(8))) _Float16 f16x8;
typedef __attribute__((ext_vector_type(4))) float    f32x4;

#define STRH 264   // LDS row stride in fp16: 528B = 132 dw == 4 mod 32 banks
                   // -> A-frag ds_read_b128 lands 8 lanes/bank (wave64 minimum)

// ws layout in floats:
//   [0)        W1aT  128*256 = 32768   fp32
//   [32768)    W1bT  128*256 = 32768   fp32
//   [65536)    W2h   256*256 fp16  (native [o][k] = MFMA B fragment)
//   [98304)    W2l   256*256 fp16
//   [131072)   W3h   256*256 fp16
//   [163840)   W3l   256*256 fp16
//   [196608)   A1    2048*256 fp32
//   [720896)   B1    2048*256 fp32
//   [1245184)  partial 4096*256 fp32
// total 2293760 floats = 8.75 MB

__global__ void prep_w(const float* __restrict__ W1,
                       const float* __restrict__ W2,
                       const float* __restrict__ W3,
                       float* __restrict__ ws) {
    int e = blockIdx.x * 256 + threadIdx.x;   // 0..65535
    int hi = e >> 8;
    int o  = e & 255;
    if (e < 32768) {
        ws[e]         = W1[o * 256 + hi];        // W1aT[h][o]
        ws[32768 + e] = W1[o * 256 + 128 + hi];  // W1bT[h][o]
    }
    f16* W2h = (f16*)(ws + 65536);
    f16* W2l = (f16*)(ws + 98304);
    f16* W3h = (f16*)(ws + 131072);
    f16* W3l = (f16*)(ws + 163840);
    float w2 = W2[e];
    f16 h2 = (f16)w2;
    W2h[e] = h2;
    W2l[e] = (f16)(w2 - (float)h2);
    float w3 = W3[e];
    f16 h3 = (f16)w3;
    W3h[e] = h3;
    W3l[e] = (f16)(w3 - (float)h3);
}

__global__ void prep_ab(const float* __restrict__ enc,
                        const float* __restrict__ ws,
                        float* __restrict__ A1,
                        float* __restrict__ B1) {
    __shared__ float es[128];
    int row = blockIdx.x;       // 0..2047 = (b*16+n)*8+k
    int o = threadIdx.x;        // 0..255
    if (o < 128) es[o] = enc[row * 128 + o];
    __syncthreads();
    const float* __restrict__ W1aT = ws;
    const float* __restrict__ W1bT = ws + 32768;
    float a = 0.f, bv = 0.f;
#pragma unroll 8
    for (int h = 0; h < 128; ++h) {
        float ev = es[h];
        a  += ev * W1aT[h * 256 + o];
        bv += ev * W1bT[h * 256 + o];
    }
    A1[row * 256 + o] = a;
    B1[row * 256 + o] = bv;
}

__global__ __launch_bounds__(256, 4)
void relnet_main(const float* __restrict__ A1, const float* __restrict__ B1,
                 const f16* __restrict__ W2h, const f16* __restrict__ W2l,
                 const f16* __restrict__ W3h, const f16* __restrict__ W3l,
                 float* __restrict__ partial) {
    // single fp16 buffer, reused for o1 then o2.  33.8 KB -> 4 blocks/CU.
    __shared__ alignas(16) f16 oh[64][STRH];

    const int n2 = blockIdx.x, n1 = blockIdx.y, b = blockIdx.z;
    const int tid  = threadIdx.x;
    const int lane = tid & 63;
    const int w    = tid >> 6;      // wave 0..3
    const int lr   = lane & 15;     // frag row (A) / frag col (B,D)
    const int lg   = lane >> 4;     // k-group (A/B) / row-group (D)
    const int cb   = w * 64;        // wave's 64-col slice
    const int ko   = lg * 8;

    // ---- build o1[64][256] = fp16(relu(A[k1]+Bv[k2])), vectorized ----
    {
        const int r = tid >> 2, g = tid & 3;      // row 0..63, 64-feat group
        const int k1 = r >> 3, k2 = r & 7;
        const float* __restrict__ Ar = A1 + ((b * 16 + n1) * 8 + k1) * 256 + g * 64;
        const float* __restrict__ Br = B1 + ((b * 16 + n2) * 8 + k2) * 256 + g * 64;
#pragma unroll
        for (int half = 0; half < 2; ++half) {
            f16 hv[32];
#pragma unroll
            for (int q = 0; q < 8; ++q) {
                float4 av = *(const float4*)&Ar[half * 32 + q * 4];
                float4 bv = *(const float4*)&Br[half * 32 + q * 4];
                hv[q * 4 + 0] = (f16)fmaxf(av.x + bv.x, 0.f);
                hv[q * 4 + 1] = (f16)fmaxf(av.y + bv.y, 0.f);
                hv[q * 4 + 2] = (f16)fmaxf(av.z + bv.z, 0.f);
                hv[q * 4 + 3] = (f16)fmaxf(av.w + bv.w, 0.f);
            }
#pragma unroll
            for (int s = 0; s < 4; ++s)
                *(f16x8*)&oh[r][g * 64 + half * 32 + s * 8] =
                    *(const f16x8*)&hv[s * 8];
        }
    }
    __syncthreads();

    f32x4 acc[4][4];

    // ================= layer 2 =================
#pragma unroll
    for (int fm = 0; fm < 4; ++fm)
#pragma unroll
        for (int fn = 0; fn < 4; ++fn) acc[fm][fn] = (f32x4){0.f, 0.f, 0.f, 0.f};

    __builtin_amdgcn_s_setprio(1);
#pragma unroll
    for (int ks = 0; ks < 8; ++ks) {
        f16x8 a[4];
#pragma unroll
        for (int fm = 0; fm < 4; ++fm)
            a[fm] = *(const f16x8*)&oh[fm * 16 + lr][ks * 32 + ko];
#pragma unroll
        for (int fn = 0; fn < 4; ++fn) {
            const int col = cb + fn * 16 + lr;
            f16x8 bh = *(const f16x8*)&W2h[col * 256 + ks * 32 + ko];
            f16x8 bl = *(const f16x8*)&W2l[col * 256 + ks * 32 + ko];
#pragma unroll
            for (int fm = 0; fm < 4; ++fm)
                acc[fm][fn] = __builtin_amdgcn_mfma_f32_16x16x32_f16(a[fm], bh, acc[fm][fn], 0, 0, 0);
#pragma unroll
            for (int fm = 0; fm < 4; ++fm)
                acc[fm][fn] = __builtin_amdgcn_mfma_f32_16x16x32_f16(a[fm], bl, acc[fm][fn], 0, 0, 0);
        }
    }
    __builtin_amdgcn_s_setprio(0);
    __syncthreads();   // all layer-2 LDS reads done

    // write o2 = fp16(relu(acc)) back into oh
    // D frag: col = lane&15 (-> cb+fn*16+lr), row = lg*4 + j within 16x16
#pragma unroll
    for (int fm = 0; fm < 4; ++fm)
#pragma unroll
        for (int fn = 0; fn < 4; ++fn)
#pragma unroll
            for (int j = 0; j < 4; ++j) {
                float v = fmaxf(acc[fm][fn][j], 0.f);
                oh[fm * 16 + lg * 4 + j][cb + fn * 16 + lr] = (f16)v;
            }
    __syncthreads();

    // ================= layer 3 =================
#pragma unroll
    for (int fm = 0; fm < 4; ++fm)
#pragma unroll
        for (int fn = 0; fn < 4; ++fn) acc[fm][fn] = (f32x4){0.f, 0.f, 0.f, 0.f};

    __builtin_amdgcn_s_setprio(1);
#pragma unroll
    for (int ks = 0; ks < 8; ++ks) {
        f16x8 a[4];
#pragma unroll
        for (int fm = 0; fm < 4; ++fm)
            a[fm] = *(const f16x8*)&oh[fm * 16 + lr][ks * 32 + ko];
#pragma unroll
        for (int fn = 0; fn < 4; ++fn) {
            const int col = cb + fn * 16 + lr;
            f16x8 bh = *(const f16x8*)&W3h[col * 256 + ks * 32 + ko];
            f16x8 bl = *(const f16x8*)&W3l[col * 256 + ks * 32 + ko];
#pragma unroll
            for (int fm = 0; fm < 4; ++fm)
                acc[fm][fn] = __builtin_amdgcn_mfma_f32_16x16x32_f16(a[fm], bh, acc[fm][fn], 0, 0, 0);
#pragma unroll
            for (int fm = 0; fm < 4; ++fm)
                acc[fm][fn] = __builtin_amdgcn_mfma_f32_16x16x32_f16(a[fm], bl, acc[fm][fn], 0, 0, 0);
        }
    }
    __builtin_amdgcn_s_setprio(0);

    // ---- relu + row-sum over the 64 rows ----
    float po[4] = {0.f, 0.f, 0.f, 0.f};
#pragma unroll
    for (int fn = 0; fn < 4; ++fn)
#pragma unroll
        for (int fm = 0; fm < 4; ++fm)
#pragma unroll
            for (int j = 0; j < 4; ++j)
                po[fn] += fmaxf(acc[fm][fn][j], 0.f);
#pragma unroll
    for (int fn = 0; fn < 4; ++fn) {
        po[fn] += __shfl_xor(po[fn], 16);
        po[fn] += __shfl_xor(po[fn], 32);
    }
    if (lane < 16) {
        float* pb = partial + (((b * 16 + n1) * 16 + n2) * 256) + cb + lane;
#pragma unroll
        for (int fn = 0; fn < 4; ++fn) pb[fn * 16] = po[fn];
    }
}

__global__ void reduce_mean(const float* __restrict__ partial,
                            float* __restrict__ out) {
    int e = blockIdx.x * 256 + threadIdx.x;  // (b*16+n1)*256+o
    int bn1 = e >> 8, o = e & 255;
    float s = 0.f;
#pragma unroll
    for (int n2 = 0; n2 < 16; ++n2)
        s += partial[(bn1 * 16 + n2) * 256 + o];
    out[e] = s * (1.0f / 1024.0f);
}

extern "C" void kernel_launch(void* const* d_in, const int* in_sizes, int n_in,
                              void* d_out, int out_size, void* d_ws, size_t ws_size,
                              hipStream_t stream) {
    const float* enc = (const float*)d_in[0];
    const float* W1  = (const float*)d_in[1];
    const float* W2  = (const float*)d_in[2];
    const float* W3  = (const float*)d_in[3];
    float* ws  = (float*)d_ws;
    float* out = (float*)d_out;

    const f16* W2h = (const f16*)(ws + 65536);
    const f16* W2l = (const f16*)(ws + 98304);
    const f16* W3h = (const f16*)(ws + 131072);
    const f16* W3l = (const f16*)(ws + 163840);
    float* A1   = ws + 196608;
    float* B1   = ws + 720896;
    float* part = ws + 1245184;

    prep_w<<<256, 256, 0, stream>>>(W1, W2, W3, ws);
    prep_ab<<<2048, 256, 0, stream>>>(enc, ws, A1, B1);
    relnet_main<<<dim3(16, 16, 16), 256, 0, stream>>>(A1, B1, W2h, W2l, W3h, W3l, part);
    reduce_mean<<<256, 256, 0, stream>>>(part, out);
}